// Round 1
// baseline (627.214 us; speedup 1.0000x reference)
//
#include <hip/hip_runtime.h>
#include <hip/hip_bf16.h>

// TaylorMap: x_{t+1} = x_t + W0 + W1^T x + sum_{i,j} x_i x_j W2[i,j,:], 7 steps.
// Strategy: per-workgroup-resident state (64 batch rows in LDS, fp32),
// quadratic term as sum_i x_i * (T_i^T @ x^T) via 32x32x16 bf16 MFMA with the
// batch on the MFMA *column* so the per-i scale is one scalar per lane.
// W is pre-packed into MFMA A-fragment order (bf16) by prep_kernel into d_ws.

#define DSTATE 128
#define BATCH  16384
#define NSTEPS 7
#define NI     130      // 128 quadratic i's + 1 linear (scale row = 1.0) + 1 dummy (zeros)
#define BT     64       // batch rows per workgroup

typedef __attribute__((ext_vector_type(8)))  short  short8;   // 8 bf16 = 4 VGPRs
typedef __attribute__((ext_vector_type(16))) float  f32x16;   // MFMA 32x32 C/D

__device__ __forceinline__ unsigned short f2bf(float f){
    unsigned int u = __float_as_uint(f);
    u += 0x7fff + ((u >> 16) & 1);          // round-to-nearest-even
    return (unsigned short)(u >> 16);
}

// Pack W (fp32 [16513][128]) into bf16 MFMA-A fragments.
// frag id g = ((t*NI + i)*8 + s)*64 + lane, elements e=0..7:
//   A[m][k] with m = lane&31 -> d = 32t+m ;  k = (lane>>5)*8+e -> j = 16s+k
//   i<128 : W2[i][j][d] = W[(129 + 128*i + j)*128 + d]
//   i==128: W1[j][d]    = W[(1 + j)*128 + d]          (scale handled as 1.0)
//   i==129: 0                                         (dummy, scale 0; keeps i-count even)
__global__ void prep_kernel(const float* __restrict__ W, short8* __restrict__ A){
    int gid = blockIdx.x * 256 + threadIdx.x;
    const int nfrag = 4 * NI * 8 * 64;
    if (gid >= nfrag) return;
    int lane = gid & 63;
    int r    = gid >> 6;
    int s    = r & 7;  r >>= 3;
    int i    = r % NI;
    int t    = r / NI;
    int d    = t * 32 + (lane & 31);
    int jb   = s * 16 + (lane >> 5) * 8;
    union { short8 v; unsigned short u[8]; } fr;
#pragma unroll
    for (int e = 0; e < 8; ++e){
        int j = jb + e;
        float v;
        if      (i < 128)  v = W[(129 + 128 * i + j) * 128 + d];
        else if (i == 128) v = W[(1 + j) * 128 + d];
        else               v = 0.0f;
        fr.u[e] = f2bf(v);
    }
    A[gid] = fr.v;
}

__global__ __launch_bounds__(512, 2)
void taylor_kernel(const float* __restrict__ X, const float* __restrict__ W,
                   const float* __restrict__ tini, const float* __restrict__ lini,
                   const short8* __restrict__ A, float* __restrict__ out)
{
    // state x in LDS, d-major [row=j/d][col=b], stride 64 -> all accesses are
    // 2 lanes/bank (free). rows 128=ones (linear-term scale), 129=zeros (dummy).
    __shared__ float x_lds[NI * BT];
    __shared__ float w0_lds[DSTATE];

    const int tid  = threadIdx.x;
    const int lane = tid & 63;
    const int w    = tid >> 6;           // wave 0..7
    const int t    = w & 3;              // d-tile (32 dims)
    const int half = lane >> 5;
    const int bsub = (w >> 2) * 32;      // batch half
    const int bcol = bsub + (lane & 31); // this lane's batch column (fixed!)
    const int b0   = blockIdx.x * BT;

    // ---- init state: x0 = [X | t_init | l_init] ----
#pragma unroll
    for (int it = 0; it < 16; ++it){
        int entry = tid + it * 512;      // entry = b*128 + d (coalesced X reads)
        int b = entry >> 7, d = entry & 127;
        float v;
        if      (d < 120) v = X[(b0 + b) * 120 + d];
        else if (d < 124) v = tini[d - 120];
        else              v = lini[d - 124];
        x_lds[d * BT + b] = v;
    }
    if (tid < BT){ x_lds[128 * BT + tid] = 1.0f; x_lds[129 * BT + tid] = 0.0f; }
    if (tid < DSTATE) w0_lds[tid] = W[tid];   // bias row W[0][:]

    // wave's A stream base (short8 units)
    const short8* Aw = A + (size_t)(t * NI * 8) * 64 + lane;

    for (int step = 0; step < NSTEPS; ++step){
        __syncthreads();                 // x_lds stable for this step

        // ---- B fragments: x^T bf16, K=128 in 8 slices, resident all step ----
        short8 bfrag[8];
#pragma unroll
        for (int s = 0; s < 8; ++s){
            union { short8 v; unsigned short u[8]; } fr;
#pragma unroll
            for (int e = 0; e < 8; ++e){
                int j = s * 16 + half * 8 + e;
                fr.u[e] = f2bf(x_lds[j * BT + bcol]);
            }
            bfrag[s] = fr.v;
        }

        // ---- acc = x_old + W0 (residual + bias folded in) ----
        f32x16 acc;
#pragma unroll
        for (int r = 0; r < 16; ++r){
            int d = 32 * t + (r & 3) + 8 * (r >> 2) + 4 * half;
            acc[r] = x_lds[d * BT + bcol] + w0_lds[d];
        }

        // ---- i-loop: acc += x_i * (T_i^T @ x^T), A double-buffered ----
        short8 abuf[2][8];
        float  scbuf[2];
        const short8* ap = Aw;
#pragma unroll
        for (int s = 0; s < 8; ++s) abuf[0][s] = ap[s * 64];
        scbuf[0] = x_lds[0 * BT + bcol];
        ap += 8 * 64;
#pragma unroll 2
        for (int i = 0; i < NI; ++i){
            const int cur = i & 1, nxt = cur ^ 1;
            if (i < NI - 1){
#pragma unroll
                for (int s = 0; s < 8; ++s) abuf[nxt][s] = ap[s * 64];
                scbuf[nxt] = x_lds[(i + 1) * BT + bcol];
                ap += 8 * 64;
            }
            f32x16 Y = {};
#pragma unroll
            for (int s = 0; s < 8; ++s)
                Y = __builtin_amdgcn_mfma_f32_32x32x16_bf16(abuf[cur][s], bfrag[s], Y, 0, 0, 0);
            acc += scbuf[cur] * Y;       // fp32 scale-accumulate, scalar per lane
        }

        __syncthreads();                 // everyone done reading x_old
        if (step < NSTEPS - 1){
#pragma unroll
            for (int r = 0; r < 16; ++r){
                int d = 32 * t + (r & 3) + 8 * (r >> 2) + 4 * half;
                x_lds[d * BT + bcol] = acc[r];
            }
        } else {
            // output dims 120..123 live in d-tile 3, regs 12..15, half==0
            if (t == 3 && half == 0){
                float4 o = make_float4(acc[12], acc[13], acc[14], acc[15]);
                *(float4*)(out + (size_t)(b0 + bcol) * 4) = o;
            }
        }
    }
}

extern "C" void kernel_launch(void* const* d_in, const int* in_sizes, int n_in,
                              void* d_out, int out_size, void* d_ws, size_t ws_size,
                              hipStream_t stream)
{
    const float* X  = (const float*)d_in[0];
    const float* W  = (const float*)d_in[1];
    const float* ti = (const float*)d_in[2];
    const float* li = (const float*)d_in[3];
    float* out      = (float*)d_out;
    short8* A       = (short8*)d_ws;     // needs 4*130*8*64*16 B = 4.26 MB of ws

    const int nfrag = 4 * NI * 8 * 64;
    prep_kernel<<<(nfrag + 255) / 256, 256, 0, stream>>>(W, A);
    taylor_kernel<<<BATCH / BT, 512, 0, stream>>>(X, W, ti, li, A, out);
}